// Round 12
// baseline (141.862 us; speedup 1.0000x reference)
//
#include <hip/hip_runtime.h>

typedef __bf16 bf16;
typedef __bf16 bf16x4 __attribute__((ext_vector_type(4)));
typedef __bf16 bf16x8 __attribute__((ext_vector_type(8)));
typedef _Float16 f16;
typedef _Float16 f16x2 __attribute__((ext_vector_type(2)));
typedef _Float16 f16x4 __attribute__((ext_vector_type(4)));
typedef _Float16 f16x8 __attribute__((ext_vector_type(8)));
typedef float f32x4 __attribute__((ext_vector_type(4)));
typedef unsigned int u32x4 __attribute__((ext_vector_type(4)));

#define MFMA16 __builtin_amdgcn_mfma_f32_16x16x32_bf16
#define MFMA16H __builtin_amdgcn_mfma_f32_16x16x32_f16

// async 16B/lane global->LDS copy; HW scatters lane i to lds + i*16 (wave-uniform base)
__device__ __forceinline__ void async16(void* lds, const void* g) {
    __builtin_amdgcn_global_load_lds((const __attribute__((address_space(1))) unsigned int*)g,
                                     (__attribute__((address_space(3))) unsigned int*)lds, 16, 0, 0);
}

// packed f32x2 -> f16x2 (cvt_pkrtz returns __fp16-based vector; bit-cast to _Float16-based)
__device__ __forceinline__ f16x2 pkrtz(float a, float b) {
    return __builtin_bit_cast(f16x2, __builtin_amdgcn_cvt_pkrtz(a, b));
}

// ---------------------------------------------------------------------------
// K0 "prep": weight cvt (blocks 0..255) + three activation transposes
// (s3: 256..767, s4: 768..1023, s5: 1024..1151).
// R20: transpose store phase widened to bf16x8 (16B stores, half the insts).
__global__ __launch_bounds__(256) void k_prep(const float* __restrict__ qw, const float* __restrict__ kw,
                                              const float* __restrict__ vw, const float* __restrict__ ow,
                                              bf16* __restrict__ Wb,
                                              const float* __restrict__ s3, const float* __restrict__ s4,
                                              const float* __restrict__ s5,
                                              bf16* __restrict__ s3t, bf16* __restrict__ s45t) {
    __shared__ float T[64][65];
    int bx = blockIdx.x, t = threadIdx.x;
    if (bx < 256) {
        int tt = bx * 256 + t;
        const float* srcs[4] = {qw, kw, vw, ow};
        int which = tt >> 14;
        int idx = (tt & 16383) * 4;
        f32x4 v = *(const f32x4*)(srcs[which] + idx);
        bf16x4 o;
        o[0] = (bf16)v[0]; o[1] = (bf16)v[1]; o[2] = (bf16)v[2]; o[3] = (bf16)v[3];
        *(bf16x4*)(Wb + (size_t)which * 65536 + idx) = o;
        return;
    }
    const float* src; bf16* dst; int N, dstRows, rowOff, x, y, z;
    if (bx < 768)       { int i = bx - 256;  src = s3; dst = s3t;  N = 4096; dstRows = 4096; rowOff = 0;    x = i & 63; y = (i >> 6) & 3; z = i >> 8; }
    else if (bx < 1024) { int i = bx - 768;  src = s4; dst = s45t; N = 2048; dstRows = 3072; rowOff = 0;    x = i & 31; y = (i >> 5) & 3; z = i >> 7; }
    else                { int i = bx - 1024; src = s5; dst = s45t; N = 1024; dstRows = 3072; rowOff = 2048; x = i & 15; y = (i >> 4) & 3; z = i >> 6; }
    int c0 = y * 64, n0 = x * 64, b = z;
    const float* s = src + ((size_t)b * 256 + c0) * N + n0;
#pragma unroll
    for (int i = 0; i < 4; i++) {
        int flat = i * 256 + t;
        int row = flat >> 4;
        int col = (flat & 15) * 4;
        f32x4 v = *(const f32x4*)(s + (size_t)row * N + col);
        T[row][col + 0] = v[0]; T[row][col + 1] = v[1];
        T[row][col + 2] = v[2]; T[row][col + 3] = v[3];
    }
    __syncthreads();
#pragma unroll
    for (int i = 0; i < 2; i++) {
        int flat = i * 256 + t;
        int nrow = flat >> 3;
        int c8 = (flat & 7) * 8;
        bf16x8 o;
#pragma unroll
        for (int j = 0; j < 8; j++) o[j] = (bf16)T[c8 + j][nrow];
        *(bf16x8*)(dst + ((size_t)(b * dstRows + rowOff + n0 + nrow)) * 256 + c0 + c8) = o;
    }
}

// ---------------------------------------------------------------------------
// K1 "qkv": Q blocks 0..511 (mode 0), K 512..895 (mode 1), V 896..1279 (mode 2).
// mode 0: Q bf16 [bh][n][32], pre-scaled by 32^-.5*log2e.
// mode 1: K bf16 [bh][n'][32], n' row-permuted within 32-blocks.
// mode 2: V f16 [bh][32 d][3072 kn], kn permuted per 64-chunk by d-keyed XOR;
// operand-swapped MFMA (D^T) -> 4x f16x4 stores.
// R20: BK=64 (4 K-steps, 8 barriers); LDS image XOR-swizzled via per-lane
// GLOBAL source granule; counted-vmcnt dbuf (4 loads/step, vmcnt(4)).
__global__ __launch_bounds__(256) void k_qkv(const bf16* __restrict__ Wb,
                                             const bf16* __restrict__ s3t, const bf16* __restrict__ s45t,
                                             const float* __restrict__ qb, const float* __restrict__ kb,
                                             const float* __restrict__ vb,
                                             bf16* __restrict__ Qb, bf16* __restrict__ Kb,
                                             f16* __restrict__ Vtb, float qscale) {
    int i = blockIdx.x;
    int mode, n0, m0, b, Nrows;
    const bf16 *A, *Bt; const float* bias; float oscale = 1.0f;
    if (i < 512) {
        mode = 0; A = Wb; Bt = s3t; bias = qb; Nrows = 4096; oscale = qscale;
        n0 = (i & 63) * 64; m0 = ((i >> 6) & 3) * 64; b = i >> 8;
    } else if (i < 896) {
        unsigned j = i - 512;
        mode = 1; A = Wb + 65536; Bt = s45t; bias = kb; Nrows = 3072;
        n0 = (j % 48u) * 64; unsigned rr = j / 48u; m0 = (rr & 3) * 64; b = rr >> 2;
    } else {
        unsigned j = i - 896;
        mode = 2; A = Wb + 131072; Bt = s45t; bias = vb; Nrows = 3072;
        n0 = (j % 48u) * 64; unsigned rr = j / 48u; m0 = (rr & 3) * 64; b = rr >> 2;
    }
    __shared__ __align__(16) bf16 As[2][64 * 64];
    __shared__ __align__(16) bf16 Bs[2][64 * 64];
    int t = threadIdx.x;
    int w = t >> 6, lane = t & 63;
    int lrow = lane & 15, lk = lane >> 4;
    f32x4 acc[4] = {};
    int r8 = lane >> 3;                // 0..7 sub-row
    int g8 = (lane & 7) ^ (r8 & 7);    // pre-swizzled source granule (read XORs with row&7)
    const bf16* Ag0 = A + (size_t)(m0 + w * 16 + r8) * 256 + g8 * 8;
    const bf16* Ag1 = Ag0 + 8 * 256;
    const bf16* Bg0 = Bt + ((size_t)b * Nrows + n0 + w * 16 + r8) * 256 + g8 * 8;
    const bf16* Bg1 = Bg0 + 8 * 256;
#define STAGE_QKV(buf_, kc_)                                        \
    {                                                               \
        async16(&As[buf_][(w * 16) * 64], Ag0 + (kc_));             \
        async16(&As[buf_][(w * 16 + 8) * 64], Ag1 + (kc_));         \
        async16(&Bs[buf_][(w * 16) * 64], Bg0 + (kc_));             \
        async16(&Bs[buf_][(w * 16 + 8) * 64], Bg1 + (kc_));         \
    }
    STAGE_QKV(0, 0)
    STAGE_QKV(1, 64)
    int keyA = lrow & 7;
    for (int s4 = 0; s4 < 4; ++s4) {
        int buf = s4 & 1;
        if (s4 < 3) asm volatile("s_waitcnt vmcnt(4)" ::: "memory");
        else        asm volatile("s_waitcnt vmcnt(0)" ::: "memory");
        __builtin_amdgcn_s_barrier();
        __builtin_amdgcn_sched_barrier(0);
        bf16x8 af0 = *(const bf16x8*)(&As[buf][(w * 16 + lrow) * 64 + ((lk ^ keyA) << 3)]);
        bf16x8 af1 = *(const bf16x8*)(&As[buf][(w * 16 + lrow) * 64 + (((4 + lk) ^ keyA) << 3)]);
#pragma unroll
        for (int ct = 0; ct < 4; ct++) {
            bf16x8 b0 = *(const bf16x8*)(&Bs[buf][(ct * 16 + lrow) * 64 + ((lk ^ keyA) << 3)]);
            bf16x8 b1 = *(const bf16x8*)(&Bs[buf][(ct * 16 + lrow) * 64 + (((4 + lk) ^ keyA) << 3)]);
            if (mode == 2) {
                acc[ct] = MFMA16(b0, af0, acc[ct], 0, 0, 0);   // D^T: rows=n, cols=o
                acc[ct] = MFMA16(b1, af1, acc[ct], 0, 0, 0);
            } else {
                acc[ct] = MFMA16(af0, b0, acc[ct], 0, 0, 0);   // rows=o, cols=n
                acc[ct] = MFMA16(af1, b1, acc[ct], 0, 0, 0);
            }
        }
        __builtin_amdgcn_s_barrier();
        if (s4 < 2) STAGE_QKV(buf, (s4 + 2) * 64)
    }
#undef STAGE_QKV
    // C/D layout: col = lane&15, row = (lane>>4)*4 + reg  [verified m89/m91]
    if (mode == 2) {
        int o = m0 + w * 16 + lrow;
        int head = o >> 5;
        int dd = o & 31;
        float bs = bias[o];
        int key = dd & 7;
        f16* vrow = Vtb + ((size_t)(b * 8 + head) * 32 + dd) * 3072;
#pragma unroll
        for (int ct = 0; ct < 4; ct++) {
            int g = ct * 2 + (lk >> 1);                       // 8-elem granule of n&63
            int col = n0 + ((g ^ key) << 3) + (lk & 1) * 4;   // XOR-permuted position
            f16x4 pv;
#pragma unroll
            for (int j = 0; j < 4; j++) pv[j] = (f16)(acc[ct][j] + bs);
            *(f16x4*)(vrow + col) = pv;
        }
    } else {
        int o0 = m0 + w * 16 + lk * 4;
        f32x4 b4 = *(const f32x4*)(bias + o0);
        int head = o0 >> 5;
#pragma unroll
        for (int ct = 0; ct < 4; ct++) {
            int n = n0 + ct * 16 + lrow;
            if (mode == 0) {
                int dd = o0 & 31;
                bf16x4 pv;
#pragma unroll
                for (int j = 0; j < 4; j++) pv[j] = (bf16)((acc[ct][j] + b4[j]) * oscale);
                *(bf16x4*)(Qb + ((size_t)(b * 8 + head) * 4096 + n) * 32 + dd) = pv;
            } else {
                int dd = o0 & 31;
                int u = n & 31;
                int np = (n & ~31) | (((u >> 2) & 1) << 4) | ((u >> 3) << 2) | (u & 3);
                bf16x4 pv;
#pragma unroll
                for (int j = 0; j < 4; j++) pv[j] = (bf16)(acc[ct][j] + b4[j]);
                *(bf16x4*)(Kb + ((size_t)(b * 8 + head) * 3072 + np) * 32 + dd) = pv;
            }
        }
    }
}

// ---------------------------------------------------------------------------
// K2: attention. S^T = K·Q^T; exp2'd C/D regs form K=32 f16 B-operand for PV
// (V^T as A): out^T[d][q] += V^T·P^T. L row-sums on the MFMA pipe (ones-MFMA).
// R21: split-kn 4 -> 5 => grid 16bh x 5sp x 16q = 1280 = exactly 5 blocks/CU.
// LDS 32768 x 5 = 160KB exactly; VGPR ~84 -> 5-6 waves/SIMD admissible, so
// occupancy rises 16 -> 20 waves/CU WITHOUT any launch_bounds VGPR cap
// (R17's mistake). 24 KV tiles split {5,5,5,5,4} per sp (variable trip count).
// XCD locality: 80 % 8 == 0, so id%8->XCD pins combo%8 per XCD (10 combos).
// Per-wave q-tile 64 (4 qg); KVBLK=128; counted-vmcnt dbuf; (256,4).
__global__ __launch_bounds__(256, 4) void k_attn(const bf16* __restrict__ Q, const bf16* __restrict__ K,
                                                 const f16* __restrict__ Vt,
                                                 f16* __restrict__ Opart, float* __restrict__ Lsum) {
    int id = blockIdx.x;
    int combo = id % 80;
    int bh = combo & 15;
    int sp = combo >> 4;              // 0..4
    int q0 = (id / 80) * 256;
    int kn0 = sp * 640;
    int nt = (sp < 4) ? 5 : 4;        // tiles this block owns
    int t = threadIdx.x, w = t >> 6, lane = t & 63;
    int lrow = lane & 15, lk = lane >> 4;
    __shared__ __align__(16) char smem[32768];
    bf16* Ks = (bf16*)smem;           // [2][128*32] bf16 (buf stride 4096 elems)
    f16* Vs = (f16*)(smem + 16384);   // [2][2 sub][32*64] f16 (buf stride 4096, sub 2048)
    f16* Tq = (f16*)smem;             // epilogue: per-wave 32 x 66 (aliases Ks)
    const bf16* kbase = K + (size_t)bh * 3072 * 32;
    const f16* vbase = Vt + (size_t)bh * 32 * 3072;
    const bf16* kg = kbase + (size_t)(kn0 + w * 16 + (lane >> 2)) * 32 + (lane & 3) * 8;
    const f16* vg = vbase + (size_t)(w * 8 + (lane >> 3)) * 3072 + kn0 + (lane & 7) * 8;
    // Q as B-operand: B[k=d=lk*8+j][n=q=lrow], one frag per 16-q group
    bf16x8 aq[4];
#pragma unroll
    for (int qg = 0; qg < 4; ++qg)
        aq[qg] = *(const bf16x8*)(Q + ((size_t)bh * 4096 + q0 + w * 64 + qg * 16 + lrow) * 32 + lk * 8);
    f32x4 accO[4][2] = {};   // [q-group][d-half], out^T: row=d_local, col=q
    f32x4 accL[4] = {};      // ones-MFMA row sums (every row = full column sum)
    f32x4 zero = {};
    f16x8 vones;
#pragma unroll
    for (int j = 0; j < 8; ++j) vones[j] = (f16)1.f;
    int vkey = lrow & 7;     // V image XOR key = d&7 (same for both d-halves)
    // prologue: stage tiles 0 and 1 (4 loads each); nt >= 4 always
    async16(Ks + w * 512, kg);
    async16(Ks + 2048 + w * 512, kg + 64 * 32);
    async16(Vs + w * 512, vg);
    async16(Vs + 2048 + w * 512, vg + 64);
    {
        const bf16* kn_ = kg + 128 * 32;
        const f16* vn_ = vg + 128;
        async16(Ks + 4096 + w * 512, kn_);
        async16(Ks + 4096 + 2048 + w * 512, kn_ + 64 * 32);
        async16(Vs + 4096 + w * 512, vn_);
        async16(Vs + 4096 + 2048 + w * 512, vn_ + 64);
    }
    for (int c = 0; c < nt; ++c) {
        int buf = c & 1;
        // wait for THIS tile's 4 loads; next tile's 4 stay in flight
        if (c < nt - 1) asm volatile("s_waitcnt vmcnt(4)" ::: "memory");
        else            asm volatile("s_waitcnt vmcnt(0)" ::: "memory");
        __builtin_amdgcn_s_barrier();
        __builtin_amdgcn_sched_barrier(0);
        const bf16* ksb = Ks + buf * 4096;
        const f16* vsb0 = Vs + buf * 4096;
#pragma unroll
        for (int p = 0; p < 4; ++p) {   // four 32-kn chunks
            bf16x8 kf0 = *(const bf16x8*)(ksb + (p * 32 + lrow) * 32 + lk * 8);
            bf16x8 kf1 = *(const bf16x8*)(ksb + (p * 32 + 16 + lrow) * 32 + lk * 8);
            const f16* vsb = vsb0 + (p >> 1) * 2048;
            int gran = (((p & 1) << 2) | lk) ^ vkey;
            f16x8 vf0 = *(const f16x8*)(vsb + lrow * 64 + (gran << 3));
            f16x8 vf1 = *(const f16x8*)(vsb + (16 + lrow) * 64 + (gran << 3));
#pragma unroll
            for (int qg = 0; qg < 4; ++qg) {   // kf/vf shared across 4 qg
                f32x4 s0 = MFMA16(kf0, aq[qg], zero, 0, 0, 0);
                f32x4 s1 = MFMA16(kf1, aq[qg], zero, 0, 0, 0);
                f16x2 h0 = pkrtz(__builtin_amdgcn_exp2f(s0[0]), __builtin_amdgcn_exp2f(s0[1]));
                f16x2 h1 = pkrtz(__builtin_amdgcn_exp2f(s0[2]), __builtin_amdgcn_exp2f(s0[3]));
                f16x2 h2 = pkrtz(__builtin_amdgcn_exp2f(s1[0]), __builtin_amdgcn_exp2f(s1[1]));
                f16x2 h3 = pkrtz(__builtin_amdgcn_exp2f(s1[2]), __builtin_amdgcn_exp2f(s1[3]));
                f16x8 pk;
                pk[0] = h0[0]; pk[1] = h0[1]; pk[2] = h1[0]; pk[3] = h1[1];
                pk[4] = h2[0]; pk[5] = h2[1]; pk[6] = h3[0]; pk[7] = h3[1];
                accO[qg][0] = MFMA16H(vf0, pk, accO[qg][0], 0, 0, 0);
                accO[qg][1] = MFMA16H(vf1, pk, accO[qg][1], 0, 0, 0);
                accL[qg]    = MFMA16H(vones, pk, accL[qg], 0, 0, 0);   // row sums on MFMA pipe
            }
        }
        // all LDS reads consumed above; separate read-phase from overwrite
        __builtin_amdgcn_s_barrier();
        if (c < nt - 2) {
            const bf16* kn_ = kg + (size_t)(c + 2) * 128 * 32;
            const f16* vn_ = vg + (c + 2) * 128;
            async16(Ks + buf * 4096 + w * 512, kn_);
            async16(Ks + buf * 4096 + 2048 + w * 512, kn_ + 64 * 32);
            async16(Vs + buf * 4096 + w * 512, vn_);
            async16(Vs + buf * 4096 + 2048 + w * 512, vn_ + 64);
        }
    }
    // L: accL's K=32 MFMA reduction already covers all lk groups — no shuffles.
    int sb = sp * 16 + bh;
    if (lane < 16) {
#pragma unroll
        for (int qg = 0; qg < 4; ++qg)
            Lsum[(size_t)sb * 4096 + q0 + w * 64 + qg * 16 + lane] = accL[qg][0];
    }
    // O epilogue: same-wave LDS transpose [d][q] -> coalesced [q][d] f16 stores
    f16* tw = Tq + w * 2112;   // 32 d-rows x 66 (pad)
#pragma unroll
    for (int qg = 0; qg < 4; ++qg)
#pragma unroll
        for (int dh = 0; dh < 2; ++dh)
#pragma unroll
            for (int i = 0; i < 4; ++i)
                tw[(dh * 16 + lk * 4 + i) * 66 + qg * 16 + lrow] = (f16)accO[qg][dh][i];
    int q4 = (lane & 15) * 4, dgrp = (lane >> 4) * 8;
#pragma unroll
    for (int qq = 0; qq < 4; ++qq) {
        f16x8 ov;
#pragma unroll
        for (int dj = 0; dj < 8; ++dj) ov[dj] = tw[(dgrp + dj) * 66 + q4 + qq];
        *(f16x8*)(Opart + ((size_t)sb * 4096 + q0 + w * 64 + q4 + qq) * 32 + dgrp) = ov;
    }
}

// ---------------------------------------------------------------------------
// K3 "oln": o-projection + split-kn combine + bias + residual + LayerNorm +
// output transpose. 16 q x 256 c blocks (grid 512 = 2 blocks/CU); hoisted
// combine (f16x8 gathers over 5 split-kn partials) + counted-vmcnt async16
// A-staging.
__global__ __launch_bounds__(256) void k_oln(const bf16* __restrict__ A, const f16* __restrict__ Opart,
                                             const float* __restrict__ Ls, const float* __restrict__ bias,
                                             const bf16* __restrict__ s3t,
                                             const float* __restrict__ lnw, const float* __restrict__ lnb,
                                             float* __restrict__ out) {
    int i = blockIdx.x;
    int b = i >> 8, n0 = (i & 255) * 16;
    __shared__ __align__(16) char smem[41728];
    bf16* As = (bf16*)smem;                 // [2][256*32] bf16 = 32768 B (async16 dest, linear)
    bf16* Bs = (bf16*)(smem + 32768);       // 16 x 264 bf16 = 8448 B (GEMM phase)
    float* T = (float*)smem;                // 16 x 257 f32 = 16448 B (LN phase, aliases As)
    float* ps = (float*)(smem + 41216);     // [4 w][16 n]
    float* pq = (float*)(smem + 41472);     // [4 w][16 n] (41728 total)
    float* mu_s = (float*)(smem + 16448);   // [16] (aliases As tail, dead by then)
    float* rs_s = (float*)(smem + 16512);   // [16]
    int t = threadIdx.x, w = t >> 6, lane = t & 63;
    int lrow = lane & 15, lk = lane >> 4;
    f32x4 acc[4] = {};                      // [mt: c-64-block], 16-q tile
    const size_t SPS = (size_t)16 * 4096 * 32;   // Opart sp stride (elems)
    // A staging: granule f = (w*4+s)*64 + lane; row = f>>2, col-granule = f&3.
#define STAGE_A(buf_, kc_)                                                              \
    {                                                                                   \
        _Pragma("unroll")                                                               \
        for (int s_ = 0; s_ < 4; ++s_) {                                                \
            int f_ = (w * 4 + s_) * 64 + lane;                                          \
            async16(As + (buf_) * 8192 + f_ * 8,                                        \
                    A + (size_t)(f_ >> 2) * 256 + (kc_) + (f_ & 3) * 8);                \
        }                                                                               \
    }
    STAGE_A(0, 0)
    STAGE_A(1, 32)
    // hoisted combine: B[16 q][256 c] = (sum_sp Opart) / (sum_sp Ls), f16x8 gathers
    {
        int rB = t >> 4;                // 0..15 (q row)
        int q = n0 + rB;
        int gg = t & 15;                // 8-elem granule
#pragma unroll
        for (int cc = 0; cc < 2; ++cc) {
            int c8 = cc * 128 + gg * 8;         // 0..248 step 8
            int bh = b * 8 + (c8 >> 5);
            float lh = 0.f;
#pragma unroll
            for (int sp = 0; sp < 5; ++sp) lh += Ls[(size_t)(sp * 16 + bh) * 4096 + q];
            float rl = 1.0f / lh;
            const f16* obp = Opart + ((size_t)bh * 4096 + q) * 32 + (c8 & 31);
            float sv[8] = {};
#pragma unroll
            for (int sp = 0; sp < 5; ++sp) {
                f16x8 av = *(const f16x8*)(obp + sp * SPS);
#pragma unroll
                for (int j = 0; j < 8; ++j) sv[j] += (float)av[j];
            }
            bf16x8 bb;
#pragma unroll
            for (int j = 0; j < 8; ++j) bb[j] = (bf16)(sv[j] * rl);
            *(bf16x8*)(Bs + rB * 264 + c8) = bb;
        }
    }
    asm volatile("s_waitcnt lgkmcnt(0)" ::: "memory");   // Bs writes drained pre-barrier
    for (int s8 = 0; s8 < 8; ++s8) {
        int buf = s8 & 1;
        int kc = s8 * 32;
        if (s8 < 7) asm volatile("s_waitcnt vmcnt(4)" ::: "memory");
        else        asm volatile("s_waitcnt vmcnt(0)" ::: "memory");
        __builtin_amdgcn_s_barrier();
        __builtin_amdgcn_sched_barrier(0);
        bf16x8 bfr = *(const bf16x8*)(Bs + lrow * 264 + kc + lk * 8);
#pragma unroll
        for (int mt = 0; mt < 4; ++mt) {
            bf16x8 af = *(const bf16x8*)(As + buf * 8192 + (mt * 64 + w * 16 + lrow) * 32 + lk * 8);
            acc[mt] = MFMA16(af, bfr, acc[mt], 0, 0, 0);
        }
        __builtin_amdgcn_s_barrier();
        if (s8 < 6) STAGE_A(buf, (s8 + 2) * 32)
    }
#undef STAGE_A
    // epilogue: bias + residual; write raw values to T; accumulate LN stats
    float wsum = 0.f, wsq = 0.f;
    int n = lrow;
#pragma unroll
    for (int mt = 0; mt < 4; ++mt) {
        int c0 = mt * 64 + w * 16 + lk * 4;
        f32x4 b4 = *(const f32x4*)(bias + c0);
        bf16x4 rv = *(const bf16x4*)(s3t + ((size_t)b * 4096 + n0 + n) * 256 + c0);
#pragma unroll
        for (int j = 0; j < 4; ++j) {
            float v = acc[mt][j] + b4[j] + (float)rv[j];
            T[n * 257 + c0 + j] = v;
            wsum += v;
            wsq += v * v;
        }
    }
    wsum += __shfl_xor(wsum, 16, 64);
    wsum += __shfl_xor(wsum, 32, 64);
    wsq += __shfl_xor(wsq, 16, 64);
    wsq += __shfl_xor(wsq, 32, 64);
    if (lk == 0) {
        ps[w * 16 + lrow] = wsum;
        pq[w * 16 + lrow] = wsq;
    }
    __syncthreads();
    if (t < 16) {
        float S = ps[t] + ps[16 + t] + ps[32 + t] + ps[48 + t];
        float Q2 = pq[t] + pq[16 + t] + pq[32 + t] + pq[48 + t];
        float m = S * (1.0f / 256.0f);
        mu_s[t] = m;
        rs_s[t] = rsqrtf(Q2 * (1.0f / 256.0f) - m * m + 1e-5f);
    }
    __syncthreads();
    // write out[b][c][n0..n0+15], coalesced along n
    int cb = t >> 2, n4 = (t & 3) * 4;
#pragma unroll
    for (int cc4 = 0; cc4 < 4; ++cc4) {
        int c = cb + cc4 * 64;
        float wv = lnw[c], bv = lnb[c];
        f32x4 o;
#pragma unroll
        for (int k2 = 0; k2 < 4; ++k2)
            o[k2] = (T[(n4 + k2) * 257 + c] - mu_s[n4 + k2]) * rs_s[n4 + k2] * wv + bv;
        *(f32x4*)(out + ((size_t)b * 256 + c) * 4096 + n0 + n4) = o;
    }
}

// ---------------------------------------------------------------------------
extern "C" void kernel_launch(void* const* d_in, const int* in_sizes, int n_in,
                              void* d_out, int out_size, void* d_ws, size_t ws_size,
                              hipStream_t stream) {
    const float* s3  = (const float*)d_in[0];
    const float* s4  = (const float*)d_in[1];
    const float* s5  = (const float*)d_in[2];
    const float* qw  = (const float*)d_in[3];
    const float* qb  = (const float*)d_in[4];
    const float* kw  = (const float*)d_in[5];
    const float* kb  = (const float*)d_in[6];
    const float* vw  = (const float*)d_in[7];
    const float* vb  = (const float*)d_in[8];
    const float* ow  = (const float*)d_in[9];
    const float* ob  = (const float*)d_in[10];
    const float* lnw = (const float*)d_in[11];
    const float* lnb = (const float*)d_in[12];
    float* out = (float*)d_out;
    char* ws = (char*)d_ws;

    // workspace layout (~39 MB peak):
    bf16* Wb    = (bf16*)(ws);                          // 512 KB @ 0
    bf16* s3t   = (bf16*)(ws + (512ull << 10));         // 4 MB  @ 0.5 MB (live till k_oln)
    bf16* s45t  = (bf16*)(ws + (4608ull << 10));        // 3 MB  @ 4.5 MB
    bf16* Qb    = (bf16*)(ws + (7680ull << 10));        // 4 MB  @ 7.5 MB
    bf16* Kb    = Qb + (2ull * 8 * 4096 * 32);          // 3 MB  @ 11.5 MB
    f16*  Vtb   = (f16*)(Kb + (2ull * 8 * 3072 * 32));  // 3 MB  @ 14.5 MB
    f16*  Opart = (f16*)(ws + (17920ull << 10));        // 20 MB @ 17.5 MB (f16 [5sp][16bh][4096q][32d])
    float* Lsum = (float*)(ws + (38400ull << 10));      // 1.25 MB @ 37.5 MB

    const float qscale = 0.17677669529663688f * 1.4426950408889634f;  // 32^-0.5 * log2(e)

    k_prep<<<1152, 256, 0, stream>>>(qw, kw, vw, ow, Wb, s3, s4, s5, s3t, s45t);
    k_qkv<<<1280, 256, 0, stream>>>(Wb, s3t, s45t, qb, kb, vb, Qb, Kb, Vtb, qscale);
    k_attn<<<1280, 256, 0, stream>>>(Qb, Kb, Vtb, Opart, Lsum);
    k_oln<<<512, 256, 0, stream>>>(Wb + 196608, Opart, Lsum, ob, s3t, lnw, lnb, out);
}

// Round 13
// 138.032 us; speedup vs baseline: 1.0277x; 1.0277x over previous
//
#include <hip/hip_runtime.h>

typedef __bf16 bf16;
typedef __bf16 bf16x4 __attribute__((ext_vector_type(4)));
typedef __bf16 bf16x8 __attribute__((ext_vector_type(8)));
typedef _Float16 f16;
typedef _Float16 f16x2 __attribute__((ext_vector_type(2)));
typedef _Float16 f16x4 __attribute__((ext_vector_type(4)));
typedef _Float16 f16x8 __attribute__((ext_vector_type(8)));
typedef float f32x4 __attribute__((ext_vector_type(4)));
typedef unsigned int u32x4 __attribute__((ext_vector_type(4)));

#define MFMA16 __builtin_amdgcn_mfma_f32_16x16x32_bf16
#define MFMA16H __builtin_amdgcn_mfma_f32_16x16x32_f16

// async 16B/lane global->LDS copy; HW scatters lane i to lds + i*16 (wave-uniform base)
__device__ __forceinline__ void async16(void* lds, const void* g) {
    __builtin_amdgcn_global_load_lds((const __attribute__((address_space(1))) unsigned int*)g,
                                     (__attribute__((address_space(3))) unsigned int*)lds, 16, 0, 0);
}

// packed f32x2 -> f16x2 (cvt_pkrtz returns __fp16-based vector; bit-cast to _Float16-based)
__device__ __forceinline__ f16x2 pkrtz(float a, float b) {
    return __builtin_bit_cast(f16x2, __builtin_amdgcn_cvt_pkrtz(a, b));
}

// ---------------------------------------------------------------------------
// K0 "prep": weight cvt (blocks 0..255) + three activation transposes
// (s3: 256..767, s4: 768..1023, s5: 1024..1151).
// R20: transpose store phase widened to bf16x8 (16B stores, half the insts).
__global__ __launch_bounds__(256) void k_prep(const float* __restrict__ qw, const float* __restrict__ kw,
                                              const float* __restrict__ vw, const float* __restrict__ ow,
                                              bf16* __restrict__ Wb,
                                              const float* __restrict__ s3, const float* __restrict__ s4,
                                              const float* __restrict__ s5,
                                              bf16* __restrict__ s3t, bf16* __restrict__ s45t) {
    __shared__ float T[64][65];
    int bx = blockIdx.x, t = threadIdx.x;
    if (bx < 256) {
        int tt = bx * 256 + t;
        const float* srcs[4] = {qw, kw, vw, ow};
        int which = tt >> 14;
        int idx = (tt & 16383) * 4;
        f32x4 v = *(const f32x4*)(srcs[which] + idx);
        bf16x4 o;
        o[0] = (bf16)v[0]; o[1] = (bf16)v[1]; o[2] = (bf16)v[2]; o[3] = (bf16)v[3];
        *(bf16x4*)(Wb + (size_t)which * 65536 + idx) = o;
        return;
    }
    const float* src; bf16* dst; int N, dstRows, rowOff, x, y, z;
    if (bx < 768)       { int i = bx - 256;  src = s3; dst = s3t;  N = 4096; dstRows = 4096; rowOff = 0;    x = i & 63; y = (i >> 6) & 3; z = i >> 8; }
    else if (bx < 1024) { int i = bx - 768;  src = s4; dst = s45t; N = 2048; dstRows = 3072; rowOff = 0;    x = i & 31; y = (i >> 5) & 3; z = i >> 7; }
    else                { int i = bx - 1024; src = s5; dst = s45t; N = 1024; dstRows = 3072; rowOff = 2048; x = i & 15; y = (i >> 4) & 3; z = i >> 6; }
    int c0 = y * 64, n0 = x * 64, b = z;
    const float* s = src + ((size_t)b * 256 + c0) * N + n0;
#pragma unroll
    for (int i = 0; i < 4; i++) {
        int flat = i * 256 + t;
        int row = flat >> 4;
        int col = (flat & 15) * 4;
        f32x4 v = *(const f32x4*)(s + (size_t)row * N + col);
        T[row][col + 0] = v[0]; T[row][col + 1] = v[1];
        T[row][col + 2] = v[2]; T[row][col + 3] = v[3];
    }
    __syncthreads();
#pragma unroll
    for (int i = 0; i < 2; i++) {
        int flat = i * 256 + t;
        int nrow = flat >> 3;
        int c8 = (flat & 7) * 8;
        bf16x8 o;
#pragma unroll
        for (int j = 0; j < 8; j++) o[j] = (bf16)T[c8 + j][nrow];
        *(bf16x8*)(dst + ((size_t)(b * dstRows + rowOff + n0 + nrow)) * 256 + c0 + c8) = o;
    }
}

// ---------------------------------------------------------------------------
// K1 "qkv": Q blocks 0..511 (mode 0), K 512..895 (mode 1), V 896..1279 (mode 2).
// mode 0: Q bf16 [bh][n][32], pre-scaled by 32^-.5*log2e.
// mode 1: K bf16 [bh][n'][32], n' row-permuted within 32-blocks.
// mode 2: V f16 [bh][32 d][3072 kn], kn permuted per 64-chunk by d-keyed XOR;
// operand-swapped MFMA (D^T) -> 4x f16x4 stores.
// R20: BK=64 (4 K-steps, 8 barriers); LDS image XOR-swizzled via per-lane
// GLOBAL source granule; counted-vmcnt dbuf (4 loads/step, vmcnt(4)).
__global__ __launch_bounds__(256) void k_qkv(const bf16* __restrict__ Wb,
                                             const bf16* __restrict__ s3t, const bf16* __restrict__ s45t,
                                             const float* __restrict__ qb, const float* __restrict__ kb,
                                             const float* __restrict__ vb,
                                             bf16* __restrict__ Qb, bf16* __restrict__ Kb,
                                             f16* __restrict__ Vtb, float qscale) {
    int i = blockIdx.x;
    int mode, n0, m0, b, Nrows;
    const bf16 *A, *Bt; const float* bias; float oscale = 1.0f;
    if (i < 512) {
        mode = 0; A = Wb; Bt = s3t; bias = qb; Nrows = 4096; oscale = qscale;
        n0 = (i & 63) * 64; m0 = ((i >> 6) & 3) * 64; b = i >> 8;
    } else if (i < 896) {
        unsigned j = i - 512;
        mode = 1; A = Wb + 65536; Bt = s45t; bias = kb; Nrows = 3072;
        n0 = (j % 48u) * 64; unsigned rr = j / 48u; m0 = (rr & 3) * 64; b = rr >> 2;
    } else {
        unsigned j = i - 896;
        mode = 2; A = Wb + 131072; Bt = s45t; bias = vb; Nrows = 3072;
        n0 = (j % 48u) * 64; unsigned rr = j / 48u; m0 = (rr & 3) * 64; b = rr >> 2;
    }
    __shared__ __align__(16) bf16 As[2][64 * 64];
    __shared__ __align__(16) bf16 Bs[2][64 * 64];
    int t = threadIdx.x;
    int w = t >> 6, lane = t & 63;
    int lrow = lane & 15, lk = lane >> 4;
    f32x4 acc[4] = {};
    int r8 = lane >> 3;                // 0..7 sub-row
    int g8 = (lane & 7) ^ (r8 & 7);    // pre-swizzled source granule (read XORs with row&7)
    const bf16* Ag0 = A + (size_t)(m0 + w * 16 + r8) * 256 + g8 * 8;
    const bf16* Ag1 = Ag0 + 8 * 256;
    const bf16* Bg0 = Bt + ((size_t)b * Nrows + n0 + w * 16 + r8) * 256 + g8 * 8;
    const bf16* Bg1 = Bg0 + 8 * 256;
#define STAGE_QKV(buf_, kc_)                                        \
    {                                                               \
        async16(&As[buf_][(w * 16) * 64], Ag0 + (kc_));             \
        async16(&As[buf_][(w * 16 + 8) * 64], Ag1 + (kc_));         \
        async16(&Bs[buf_][(w * 16) * 64], Bg0 + (kc_));             \
        async16(&Bs[buf_][(w * 16 + 8) * 64], Bg1 + (kc_));         \
    }
    STAGE_QKV(0, 0)
    STAGE_QKV(1, 64)
    int keyA = lrow & 7;
    for (int s4 = 0; s4 < 4; ++s4) {
        int buf = s4 & 1;
        if (s4 < 3) asm volatile("s_waitcnt vmcnt(4)" ::: "memory");
        else        asm volatile("s_waitcnt vmcnt(0)" ::: "memory");
        __builtin_amdgcn_s_barrier();
        __builtin_amdgcn_sched_barrier(0);
        bf16x8 af0 = *(const bf16x8*)(&As[buf][(w * 16 + lrow) * 64 + ((lk ^ keyA) << 3)]);
        bf16x8 af1 = *(const bf16x8*)(&As[buf][(w * 16 + lrow) * 64 + (((4 + lk) ^ keyA) << 3)]);
#pragma unroll
        for (int ct = 0; ct < 4; ct++) {
            bf16x8 b0 = *(const bf16x8*)(&Bs[buf][(ct * 16 + lrow) * 64 + ((lk ^ keyA) << 3)]);
            bf16x8 b1 = *(const bf16x8*)(&Bs[buf][(ct * 16 + lrow) * 64 + (((4 + lk) ^ keyA) << 3)]);
            if (mode == 2) {
                acc[ct] = MFMA16(b0, af0, acc[ct], 0, 0, 0);   // D^T: rows=n, cols=o
                acc[ct] = MFMA16(b1, af1, acc[ct], 0, 0, 0);
            } else {
                acc[ct] = MFMA16(af0, b0, acc[ct], 0, 0, 0);   // rows=o, cols=n
                acc[ct] = MFMA16(af1, b1, acc[ct], 0, 0, 0);
            }
        }
        __builtin_amdgcn_s_barrier();
        if (s4 < 2) STAGE_QKV(buf, (s4 + 2) * 64)
    }
#undef STAGE_QKV
    // C/D layout: col = lane&15, row = (lane>>4)*4 + reg  [verified m89/m91]
    if (mode == 2) {
        int o = m0 + w * 16 + lrow;
        int head = o >> 5;
        int dd = o & 31;
        float bs = bias[o];
        int key = dd & 7;
        f16* vrow = Vtb + ((size_t)(b * 8 + head) * 32 + dd) * 3072;
#pragma unroll
        for (int ct = 0; ct < 4; ct++) {
            int g = ct * 2 + (lk >> 1);                       // 8-elem granule of n&63
            int col = n0 + ((g ^ key) << 3) + (lk & 1) * 4;   // XOR-permuted position
            f16x4 pv;
#pragma unroll
            for (int j = 0; j < 4; j++) pv[j] = (f16)(acc[ct][j] + bs);
            *(f16x4*)(vrow + col) = pv;
        }
    } else {
        int o0 = m0 + w * 16 + lk * 4;
        f32x4 b4 = *(const f32x4*)(bias + o0);
        int head = o0 >> 5;
#pragma unroll
        for (int ct = 0; ct < 4; ct++) {
            int n = n0 + ct * 16 + lrow;
            if (mode == 0) {
                int dd = o0 & 31;
                bf16x4 pv;
#pragma unroll
                for (int j = 0; j < 4; j++) pv[j] = (bf16)((acc[ct][j] + b4[j]) * oscale);
                *(bf16x4*)(Qb + ((size_t)(b * 8 + head) * 4096 + n) * 32 + dd) = pv;
            } else {
                int dd = o0 & 31;
                int u = n & 31;
                int np = (n & ~31) | (((u >> 2) & 1) << 4) | ((u >> 3) << 2) | (u & 3);
                bf16x4 pv;
#pragma unroll
                for (int j = 0; j < 4; j++) pv[j] = (bf16)(acc[ct][j] + b4[j]);
                *(bf16x4*)(Kb + ((size_t)(b * 8 + head) * 3072 + np) * 32 + dd) = pv;
            }
        }
    }
}

// ---------------------------------------------------------------------------
// K2: attention (R20/R19 proven config — R21's split-kn=5 hit the LDS pool
// boundary exactly, the 5th block/CU never became resident, and the 1280-grid
// ran as 4/CU x 1.25 rounds with a 3/4-idle tail: +5us. Keep 4 blocks/CU,
// one round). S^T = K·Q^T; exp2'd C/D regs form K=32 f16 B-operand for PV
// (V^T as A): out^T[d][q] += V^T·P^T. L row-sums via ones-MFMA on the matrix
// pipe. Per-wave q-tile 64 (4 qg); KVBLK=128, 6 iters, counted-vmcnt dbuf;
// split-kn=4; XCD swizzle (id&63); (256,4), VGPR ~84 (no spill).
__global__ __launch_bounds__(256, 4) void k_attn(const bf16* __restrict__ Q, const bf16* __restrict__ K,
                                                 const f16* __restrict__ Vt,
                                                 f16* __restrict__ Opart, float* __restrict__ Lsum) {
    int id = blockIdx.x;
    int bh = id & 15;
    int sp = (id >> 4) & 3;
    int q0 = (id >> 6) * 256;
    int kn0 = sp * 768;
    int t = threadIdx.x, w = t >> 6, lane = t & 63;
    int lrow = lane & 15, lk = lane >> 4;
    __shared__ __align__(16) char smem[32768];
    bf16* Ks = (bf16*)smem;           // [2][128*32] bf16 (buf stride 4096 elems)
    f16* Vs = (f16*)(smem + 16384);   // [2][2 sub][32*64] f16 (buf stride 4096, sub 2048)
    f16* Tq = (f16*)smem;             // epilogue: per-wave 32 x 66 (aliases Ks)
    const bf16* kbase = K + (size_t)bh * 3072 * 32;
    const f16* vbase = Vt + (size_t)bh * 32 * 3072;
    const bf16* kg = kbase + (size_t)(kn0 + w * 16 + (lane >> 2)) * 32 + (lane & 3) * 8;
    const f16* vg = vbase + (size_t)(w * 8 + (lane >> 3)) * 3072 + kn0 + (lane & 7) * 8;
    // Q as B-operand: B[k=d=lk*8+j][n=q=lrow], one frag per 16-q group
    bf16x8 aq[4];
#pragma unroll
    for (int qg = 0; qg < 4; ++qg)
        aq[qg] = *(const bf16x8*)(Q + ((size_t)bh * 4096 + q0 + w * 64 + qg * 16 + lrow) * 32 + lk * 8);
    f32x4 accO[4][2] = {};   // [q-group][d-half], out^T: row=d_local, col=q
    f32x4 accL[4] = {};      // ones-MFMA row sums (every row = full column sum)
    f32x4 zero = {};
    f16x8 vones;
#pragma unroll
    for (int j = 0; j < 8; ++j) vones[j] = (f16)1.f;
    int vkey = lrow & 7;     // V image XOR key = d&7 (same for both d-halves)
    // prologue: stage tiles 0 and 1 (4 loads each)
    async16(Ks + w * 512, kg);
    async16(Ks + 2048 + w * 512, kg + 64 * 32);
    async16(Vs + w * 512, vg);
    async16(Vs + 2048 + w * 512, vg + 64);
    {
        const bf16* kn_ = kg + 128 * 32;
        const f16* vn_ = vg + 128;
        async16(Ks + 4096 + w * 512, kn_);
        async16(Ks + 4096 + 2048 + w * 512, kn_ + 64 * 32);
        async16(Vs + 4096 + w * 512, vn_);
        async16(Vs + 4096 + 2048 + w * 512, vn_ + 64);
    }
    for (int c = 0; c < 6; ++c) {
        int buf = c & 1;
        // wait for THIS tile's 4 loads; next tile's 4 stay in flight
        if (c < 5) asm volatile("s_waitcnt vmcnt(4)" ::: "memory");
        else       asm volatile("s_waitcnt vmcnt(0)" ::: "memory");
        __builtin_amdgcn_s_barrier();
        __builtin_amdgcn_sched_barrier(0);
        const bf16* ksb = Ks + buf * 4096;
        const f16* vsb0 = Vs + buf * 4096;
#pragma unroll
        for (int p = 0; p < 4; ++p) {   // four 32-kn chunks
            bf16x8 kf0 = *(const bf16x8*)(ksb + (p * 32 + lrow) * 32 + lk * 8);
            bf16x8 kf1 = *(const bf16x8*)(ksb + (p * 32 + 16 + lrow) * 32 + lk * 8);
            const f16* vsb = vsb0 + (p >> 1) * 2048;
            int gran = (((p & 1) << 2) | lk) ^ vkey;
            f16x8 vf0 = *(const f16x8*)(vsb + lrow * 64 + (gran << 3));
            f16x8 vf1 = *(const f16x8*)(vsb + (16 + lrow) * 64 + (gran << 3));
#pragma unroll
            for (int qg = 0; qg < 4; ++qg) {   // kf/vf shared across 4 qg
                f32x4 s0 = MFMA16(kf0, aq[qg], zero, 0, 0, 0);
                f32x4 s1 = MFMA16(kf1, aq[qg], zero, 0, 0, 0);
                f16x2 h0 = pkrtz(__builtin_amdgcn_exp2f(s0[0]), __builtin_amdgcn_exp2f(s0[1]));
                f16x2 h1 = pkrtz(__builtin_amdgcn_exp2f(s0[2]), __builtin_amdgcn_exp2f(s0[3]));
                f16x2 h2 = pkrtz(__builtin_amdgcn_exp2f(s1[0]), __builtin_amdgcn_exp2f(s1[1]));
                f16x2 h3 = pkrtz(__builtin_amdgcn_exp2f(s1[2]), __builtin_amdgcn_exp2f(s1[3]));
                f16x8 pk;
                pk[0] = h0[0]; pk[1] = h0[1]; pk[2] = h1[0]; pk[3] = h1[1];
                pk[4] = h2[0]; pk[5] = h2[1]; pk[6] = h3[0]; pk[7] = h3[1];
                accO[qg][0] = MFMA16H(vf0, pk, accO[qg][0], 0, 0, 0);
                accO[qg][1] = MFMA16H(vf1, pk, accO[qg][1], 0, 0, 0);
                accL[qg]    = MFMA16H(vones, pk, accL[qg], 0, 0, 0);   // row sums on MFMA pipe
            }
        }
        // all LDS reads consumed above; separate read-phase from overwrite
        __builtin_amdgcn_s_barrier();
        if (c < 4) {
            const bf16* kn_ = kg + (size_t)(c + 2) * 128 * 32;
            const f16* vn_ = vg + (c + 2) * 128;
            async16(Ks + buf * 4096 + w * 512, kn_);
            async16(Ks + buf * 4096 + 2048 + w * 512, kn_ + 64 * 32);
            async16(Vs + buf * 4096 + w * 512, vn_);
            async16(Vs + buf * 4096 + 2048 + w * 512, vn_ + 64);
        }
    }
    // L: accL's K=32 MFMA reduction already covers all lk groups — no shuffles.
    int sb = sp * 16 + bh;
    if (lane < 16) {
#pragma unroll
        for (int qg = 0; qg < 4; ++qg)
            Lsum[(size_t)sb * 4096 + q0 + w * 64 + qg * 16 + lane] = accL[qg][0];
    }
    // O epilogue: same-wave LDS transpose [d][q] -> coalesced [q][d] f16 stores
    f16* tw = Tq + w * 2112;   // 32 d-rows x 66 (pad)
#pragma unroll
    for (int qg = 0; qg < 4; ++qg)
#pragma unroll
        for (int dh = 0; dh < 2; ++dh)
#pragma unroll
            for (int i = 0; i < 4; ++i)
                tw[(dh * 16 + lk * 4 + i) * 66 + qg * 16 + lrow] = (f16)accO[qg][dh][i];
    int q4 = (lane & 15) * 4, dgrp = (lane >> 4) * 8;
#pragma unroll
    for (int qq = 0; qq < 4; ++qq) {
        f16x8 ov;
#pragma unroll
        for (int dj = 0; dj < 8; ++dj) ov[dj] = tw[(dgrp + dj) * 66 + q4 + qq];
        *(f16x8*)(Opart + ((size_t)sb * 4096 + q0 + w * 64 + q4 + qq) * 32 + dgrp) = ov;
    }
}

// ---------------------------------------------------------------------------
// K3 "oln": o-projection + split-kn combine + bias + residual + LayerNorm +
// output transpose. 16 q x 256 c blocks (grid 512 = 2 blocks/CU); hoisted
// combine (f16x8 gathers over 4 split-kn partials) + counted-vmcnt async16
// A-staging.
__global__ __launch_bounds__(256) void k_oln(const bf16* __restrict__ A, const f16* __restrict__ Opart,
                                             const float* __restrict__ Ls, const float* __restrict__ bias,
                                             const bf16* __restrict__ s3t,
                                             const float* __restrict__ lnw, const float* __restrict__ lnb,
                                             float* __restrict__ out) {
    int i = blockIdx.x;
    int b = i >> 8, n0 = (i & 255) * 16;
    __shared__ __align__(16) char smem[41728];
    bf16* As = (bf16*)smem;                 // [2][256*32] bf16 = 32768 B (async16 dest, linear)
    bf16* Bs = (bf16*)(smem + 32768);       // 16 x 264 bf16 = 8448 B (GEMM phase)
    float* T = (float*)smem;                // 16 x 257 f32 = 16448 B (LN phase, aliases As)
    float* ps = (float*)(smem + 41216);     // [4 w][16 n]
    float* pq = (float*)(smem + 41472);     // [4 w][16 n] (41728 total)
    float* mu_s = (float*)(smem + 16448);   // [16] (aliases As tail, dead by then)
    float* rs_s = (float*)(smem + 16512);   // [16]
    int t = threadIdx.x, w = t >> 6, lane = t & 63;
    int lrow = lane & 15, lk = lane >> 4;
    f32x4 acc[4] = {};                      // [mt: c-64-block], 16-q tile
    const size_t SPS = (size_t)16 * 4096 * 32;   // Opart sp stride (elems)
    // A staging: granule f = (w*4+s)*64 + lane; row = f>>2, col-granule = f&3.
#define STAGE_A(buf_, kc_)                                                              \
    {                                                                                   \
        _Pragma("unroll")                                                               \
        for (int s_ = 0; s_ < 4; ++s_) {                                                \
            int f_ = (w * 4 + s_) * 64 + lane;                                          \
            async16(As + (buf_) * 8192 + f_ * 8,                                        \
                    A + (size_t)(f_ >> 2) * 256 + (kc_) + (f_ & 3) * 8);                \
        }                                                                               \
    }
    STAGE_A(0, 0)
    STAGE_A(1, 32)
    // hoisted combine: B[16 q][256 c] = (sum_sp Opart) / (sum_sp Ls), f16x8 gathers
    {
        int rB = t >> 4;                // 0..15 (q row)
        int q = n0 + rB;
        int gg = t & 15;                // 8-elem granule
#pragma unroll
        for (int cc = 0; cc < 2; ++cc) {
            int c8 = cc * 128 + gg * 8;         // 0..248 step 8
            int bh = b * 8 + (c8 >> 5);
            float lh = 0.f;
#pragma unroll
            for (int sp = 0; sp < 4; ++sp) lh += Ls[(size_t)(sp * 16 + bh) * 4096 + q];
            float rl = 1.0f / lh;
            const f16* obp = Opart + ((size_t)bh * 4096 + q) * 32 + (c8 & 31);
            float sv[8] = {};
#pragma unroll
            for (int sp = 0; sp < 4; ++sp) {
                f16x8 av = *(const f16x8*)(obp + sp * SPS);
#pragma unroll
                for (int j = 0; j < 8; ++j) sv[j] += (float)av[j];
            }
            bf16x8 bb;
#pragma unroll
            for (int j = 0; j < 8; ++j) bb[j] = (bf16)(sv[j] * rl);
            *(bf16x8*)(Bs + rB * 264 + c8) = bb;
        }
    }
    asm volatile("s_waitcnt lgkmcnt(0)" ::: "memory");   // Bs writes drained pre-barrier
    for (int s8 = 0; s8 < 8; ++s8) {
        int buf = s8 & 1;
        int kc = s8 * 32;
        if (s8 < 7) asm volatile("s_waitcnt vmcnt(4)" ::: "memory");
        else        asm volatile("s_waitcnt vmcnt(0)" ::: "memory");
        __builtin_amdgcn_s_barrier();
        __builtin_amdgcn_sched_barrier(0);
        bf16x8 bfr = *(const bf16x8*)(Bs + lrow * 264 + kc + lk * 8);
#pragma unroll
        for (int mt = 0; mt < 4; ++mt) {
            bf16x8 af = *(const bf16x8*)(As + buf * 8192 + (mt * 64 + w * 16 + lrow) * 32 + lk * 8);
            acc[mt] = MFMA16(af, bfr, acc[mt], 0, 0, 0);
        }
        __builtin_amdgcn_s_barrier();
        if (s8 < 6) STAGE_A(buf, (s8 + 2) * 32)
    }
#undef STAGE_A
    // epilogue: bias + residual; write raw values to T; accumulate LN stats
    float wsum = 0.f, wsq = 0.f;
    int n = lrow;
#pragma unroll
    for (int mt = 0; mt < 4; ++mt) {
        int c0 = mt * 64 + w * 16 + lk * 4;
        f32x4 b4 = *(const f32x4*)(bias + c0);
        bf16x4 rv = *(const bf16x4*)(s3t + ((size_t)b * 4096 + n0 + n) * 256 + c0);
#pragma unroll
        for (int j = 0; j < 4; ++j) {
            float v = acc[mt][j] + b4[j] + (float)rv[j];
            T[n * 257 + c0 + j] = v;
            wsum += v;
            wsq += v * v;
        }
    }
    wsum += __shfl_xor(wsum, 16, 64);
    wsum += __shfl_xor(wsum, 32, 64);
    wsq += __shfl_xor(wsq, 16, 64);
    wsq += __shfl_xor(wsq, 32, 64);
    if (lk == 0) {
        ps[w * 16 + lrow] = wsum;
        pq[w * 16 + lrow] = wsq;
    }
    __syncthreads();
    if (t < 16) {
        float S = ps[t] + ps[16 + t] + ps[32 + t] + ps[48 + t];
        float Q2 = pq[t] + pq[16 + t] + pq[32 + t] + pq[48 + t];
        float m = S * (1.0f / 256.0f);
        mu_s[t] = m;
        rs_s[t] = rsqrtf(Q2 * (1.0f / 256.0f) - m * m + 1e-5f);
    }
    __syncthreads();
    // write out[b][c][n0..n0+15], coalesced along n
    int cb = t >> 2, n4 = (t & 3) * 4;
#pragma unroll
    for (int cc4 = 0; cc4 < 4; ++cc4) {
        int c = cb + cc4 * 64;
        float wv = lnw[c], bv = lnb[c];
        f32x4 o;
#pragma unroll
        for (int k2 = 0; k2 < 4; ++k2)
            o[k2] = (T[(n4 + k2) * 257 + c] - mu_s[n4 + k2]) * rs_s[n4 + k2] * wv + bv;
        *(f32x4*)(out + ((size_t)b * 256 + c) * 4096 + n0 + n4) = o;
    }
}

// ---------------------------------------------------------------------------
extern "C" void kernel_launch(void* const* d_in, const int* in_sizes, int n_in,
                              void* d_out, int out_size, void* d_ws, size_t ws_size,
                              hipStream_t stream) {
    const float* s3  = (const float*)d_in[0];
    const float* s4  = (const float*)d_in[1];
    const float* s5  = (const float*)d_in[2];
    const float* qw  = (const float*)d_in[3];
    const float* qb  = (const float*)d_in[4];
    const float* kw  = (const float*)d_in[5];
    const float* kb  = (const float*)d_in[6];
    const float* vw  = (const float*)d_in[7];
    const float* vb  = (const float*)d_in[8];
    const float* ow  = (const float*)d_in[9];
    const float* ob  = (const float*)d_in[10];
    const float* lnw = (const float*)d_in[11];
    const float* lnb = (const float*)d_in[12];
    float* out = (float*)d_out;
    char* ws = (char*)d_ws;

    // workspace layout (~34.5 MB peak):
    bf16* Wb    = (bf16*)(ws);                          // 512 KB @ 0
    bf16* s3t   = (bf16*)(ws + (512ull << 10));         // 4 MB  @ 0.5 MB (live till k_oln)
    bf16* s45t  = (bf16*)(ws + (4608ull << 10));        // 3 MB  @ 4.5 MB
    bf16* Qb    = (bf16*)(ws + (7680ull << 10));        // 4 MB  @ 7.5 MB
    bf16* Kb    = Qb + (2ull * 8 * 4096 * 32);          // 3 MB  @ 11.5 MB
    f16*  Vtb   = (f16*)(Kb + (2ull * 8 * 3072 * 32));  // 3 MB  @ 14.5 MB
    f16*  Opart = (f16*)(ws + (17920ull << 10));        // 16 MB @ 17.5 MB (f16 [4sp][16bh][4096q][32d])
    float* Lsum = (float*)(ws + (34304ull << 10));      // 1 MB  @ 33.5 MB

    const float qscale = 0.17677669529663688f * 1.4426950408889634f;  // 32^-0.5 * log2(e)

    k_prep<<<1152, 256, 0, stream>>>(qw, kw, vw, ow, Wb, s3, s4, s5, s3t, s45t);
    k_qkv<<<1280, 256, 0, stream>>>(Wb, s3t, s45t, qb, kb, vb, Qb, Kb, Vtb, qscale);
    k_attn<<<1024, 256, 0, stream>>>(Qb, Kb, Vtb, Opart, Lsum);
    k_oln<<<512, 256, 0, stream>>>(Wb + 196608, Opart, Lsum, ob, s3t, lnw, lnb, out);
}